// Round 7
// baseline (427.576 us; speedup 1.0000x reference)
//
#include <hip/hip_runtime.h>
#include <hip/hip_cooperative_groups.h>
#include <math.h>
#include <float.h>

namespace cg = cooperative_groups;

#define BB 8
#define NN 8192
#define MM 4096
#define HH 128
#define WW 128

#define G    32
#define GG   (G * G)
#define CELL (1.0f / G)

// ws layout:
//   [0, 32)                 means (8 floats)
//   [256, 33056)            starts (B x (GG+1) ints)
//   [33056, 65824)          cursors (B x GG ints)
//   [65824, 1114400)        cellData (B x N float4: x, y, val, idx-bits)
//   [1114400, 1376544)      bh (64 x GG ints — per-block histograms)
#define WS_STARTS_OFF  256
#define WS_CURSORS_OFF 33056
#define WS_CELLS_OFF   65824
#define WS_BH_OFF      1114400
#define WS_NEEDED      1376544

__device__ __forceinline__ int clampi(int v, int lo, int hi) {
    return v < lo ? lo : (v > hi ? hi : v);
}

// ---------------------------------------------------------------------------
// Bilinear + mix epilogue (validated bit-exact R1/R3-R6).
// ---------------------------------------------------------------------------
__device__ __forceinline__ float epilogue(const float* __restrict__ yc_on,
                                          const float* __restrict__ means,
                                          const float* __restrict__ logit_p,
                                          int b, float px, float py, float bv) {
    const float* __restrict__ vals = yc_on + (size_t)b * HH * WW;
    const float x = px, y = py;
    int ix = clampi((int)floorf(x * 127.0f), 0, 126);
    int iy = clampi((int)floorf(y * 127.0f), 0, 126);
    const float x0 = (float)ix * (1.0f / 127.0f);
    const float x1 = (float)(ix + 1) * (1.0f / 127.0f);
    const float y0 = (float)iy * (1.0f / 127.0f);
    const float y1 = (float)(iy + 1) * (1.0f / 127.0f);
    const float wx = (x - x0) / (x1 - x0);
    const float wy = (y - y0) / (y1 - y0);
    const float v00 = vals[ix * WW + iy];
    const float v01 = vals[ix * WW + iy + 1];
    const float v10 = vals[(ix + 1) * WW + iy];
    const float v11 = vals[(ix + 1) * WW + iy + 1];
    float vi = (1.f - wx) * (1.f - wy) * v00
             + (1.f - wx) * wy         * v01
             + wx         * (1.f - wy) * v10
             + wx         * wy         * v11;
    const bool oob = (x < 0.f) || (x > 1.f) || (y < 0.f) || (y > 1.f);
    const float yon = oob ? means[b] : vi;
    const float l   = logit_p[0];
    const float mix = 1.f / (1.f + expf(-l));
    return mix * bv + (1.f - mix) * yon;
}

// ---------------------------------------------------------------------------
// Single cooperative kernel: hist -> scan -> scatter -> query, with
// grid.sync() between phases. All numeric paths identical to the
// absmax-0.0-validated kernels of R3-R6; only orchestration changed.
// Grid: 256 blocks x 1024 threads (16 waves/CU — co-resident).
// ---------------------------------------------------------------------------
__global__ __launch_bounds__(1024)
void coop_kernel(const float* __restrict__ xc_off,   // (B,N,2)
                 const float* __restrict__ yc_off,   // (B,N)
                 const float* __restrict__ yc_on,    // (B,H,W)
                 const float* __restrict__ xt,       // (B,M,2)
                 const float* __restrict__ logit_p,  // (1)
                 float* __restrict__ means,          // (B)
                 int* __restrict__ starts,           // (B,GG+1)
                 int* __restrict__ cursors,          // (B,GG)
                 float4* __restrict__ cellData,      // (B,N)
                 int* __restrict__ bh,               // (64,GG)
                 float* __restrict__ out)            // (B,M)
{
    cg::grid_group grid = cg::this_grid();
    const int blk = blockIdx.x, tid = threadIdx.x;
    __shared__ int   hist[GG];
    __shared__ int   wsum[16];
    __shared__ float partial[4];

    // ---- P1: per-block histograms (blocks 0-63) + per-batch mean (64-71) ----
    if (blk < 64) {
        hist[tid] = 0;
        __syncthreads();
        const int idx = blk * 1024 + tid;               // one point per thread
        const float2 c = ((const float2*)xc_off)[idx];
        const int gx = clampi((int)(c.x * (float)G), 0, G - 1);
        const int gy = clampi((int)(c.y * (float)G), 0, G - 1);
        atomicAdd(&hist[gx * G + gy], 1);
        __syncthreads();
        bh[blk * GG + tid] = hist[tid];                 // coalesced dump
    } else if (blk < 72) {
        // mean of yc_on[b]; EXACT 256-thread x 64-term order (bit-validated)
        const int b = blk - 64;
        float s = 0.f;
        if (tid < 256) {
            const float* p = yc_on + b * (HH * WW);
            for (int i = tid; i < HH * WW; i += 256) s += p[i];
            for (int off = 32; off > 0; off >>= 1) s += __shfl_down(s, off, 64);
        }
        if (tid < 256 && (tid & 63) == 0) partial[tid >> 6] = s;
        __syncthreads();
        if (tid == 0) {
            float t = 0.f;
            for (int i = 0; i < 4; ++i) t += partial[i];
            means[b] = t * (1.0f / (HH * WW));
        }
    }
    __threadfence();
    grid.sync();

    // ---- P2: sum 8 sub-hists + exclusive scan (blocks 0-7; validated) ----
    if (blk < 8) {
        int orig = 0;
#pragma unroll
        for (int j = 0; j < 8; ++j) orig += bh[(blk * 8 + j) * GG + tid];
        int x = orig;
        const int lane = tid & 63, wid = tid >> 6;
        for (int off = 1; off < 64; off <<= 1) {
            int y = __shfl_up(x, off, 64);
            if (lane >= off) x += y;
        }
        if (lane == 63) wsum[wid] = x;
        __syncthreads();
        if (tid < 16) {
            int w = wsum[tid];
            for (int off = 1; off < 16; off <<= 1) {
                int y = __shfl_up(w, off, 16);
                if (tid >= off) w += y;
            }
            wsum[tid] = w;
        }
        __syncthreads();
        const int incl = x + (wid ? wsum[wid - 1] : 0);
        const int excl = incl - orig;
        starts[blk * (GG + 1) + tid] = excl;
        if (tid == GG - 1) starts[blk * (GG + 1) + GG] = incl;   // == N
        cursors[blk * GG + tid] = excl;
    }
    __threadfence();
    grid.sync();

    // ---- P3: scatter (blocks 0-63, global atomic cursors spread over L2).
    // Bin-internal order nondeterministic; harmless — query uses
    // order-independent lexicographic (d2, idx) min. ----
    if (blk < 64) {
        const int idx = blk * 1024 + tid;
        const int b = idx >> 13;
        const int n = idx & (NN - 1);
        const float2 c = ((const float2*)xc_off)[idx];
        const float v = yc_off[idx];
        const int gx = clampi((int)(c.x * (float)G), 0, G - 1);
        const int gy = clampi((int)(c.y * (float)G), 0, G - 1);
        const int pos = atomicAdd(&cursors[b * GG + gx * G + gy], 1);
        cellData[(size_t)b * NN + pos] = make_float4(c.x, c.y, v, __int_as_float(n));
    }
    __threadfence();
    grid.sync();

    // ---- P4: query (all blocks; each 32-lane half serves 4 queries).
    // Validated half-wave query: parallel row gathers + 5-step xor-shuffle
    // lexicographic (d2, idx) argmin; ring re-scan idempotent. ----
    const int lane32 = tid & 31;
    const int hw = blk * 32 + (tid >> 5);                // 0..8191
#pragma unroll 1
    for (int q = 0; q < 4; ++q) {
        const int pid = hw + q * 8192;                   // covers 0..32767
        const int b = pid >> 12;                         // / MM
        const int m = pid & (MM - 1);

        const float2 pt = ((const float2*)xt)[pid];
        const float px = pt.x, py = pt.y;

        const int cx = clampi((int)(px * (float)G), 0, G - 1);
        const int cy = clampi((int)(py * (float)G), 0, G - 1);

        const int*    __restrict__ st = starts + b * (GG + 1);
        const float4* __restrict__ cd = cellData + (size_t)b * NN;

        float bd = FLT_MAX;
        float bv = 0.f;
        int   bi = 0x7fffffff;

        for (int r = 1; r <= G; ++r) {
            const int gx0 = clampi(cx - r, 0, G - 1);
            const int gx1 = clampi(cx + r, 0, G - 1);
            const int gy0 = clampi(cy - r, 0, G - 1);
            const int gy1 = clampi(cy + r, 0, G - 1);

            for (int gx = gx0; gx <= gx1; ++gx) {
                const int lo = st[gx * G + gy0];
                const int hi = st[gx * G + gy1 + 1];
                for (int j = lo + lane32; j < hi; j += 32) {
                    const float4 c = cd[j];
                    const float dx = px - c.x;
                    const float dy = py - c.y;
                    const float d2 = fmaf(dx, dx, dy * dy);
                    const int   ci = __float_as_int(c.w);
                    if (d2 < bd || (d2 == bd && ci < bi)) { bd = d2; bv = c.z; bi = ci; }
                }
            }

            for (int off = 1; off < 32; off <<= 1) {
                const float od = __shfl_xor(bd, off, 64);
                const float ov = __shfl_xor(bv, off, 64);
                const int   oi = __shfl_xor(bi, off, 64);
                if (od < bd || (od == bd && oi < bi)) { bd = od; bv = ov; bi = oi; }
            }

            const float rr = (float)r * CELL;
            if (rr * rr > bd) break;
        }

        if (lane32 == 0)
            out[(size_t)b * MM + m] = epilogue(yc_on, means, logit_p, b, px, py, bv);
    }
}

// ---------------------------------------------------------------------------
// Fallback: R1 brute-force NN (validated absmax 0.0) — only if ws too small.
// ---------------------------------------------------------------------------
#define WAVES 8
#define PTS 64
#define SLICE (NN / WAVES)

__global__ void mean_kernel(const float* __restrict__ yc_on,
                            float* __restrict__ means) {
    int b = blockIdx.x;
    const float* p = yc_on + b * (HH * WW);
    float s = 0.f;
    for (int i = threadIdx.x; i < HH * WW; i += blockDim.x) s += p[i];
    for (int off = 32; off > 0; off >>= 1) s += __shfl_down(s, off, 64);
    __shared__ float partial[4];
    int wave = threadIdx.x >> 6;
    if ((threadIdx.x & 63) == 0) partial[wave] = s;
    __syncthreads();
    if (threadIdx.x == 0) {
        float t = 0.f;
        int nw = blockDim.x >> 6;
        for (int i = 0; i < nw; ++i) t += partial[i];
        means[b] = t * (1.0f / (HH * WW));
    }
}

__global__ __launch_bounds__(WAVES * 64)
void nn_kernel(const float* __restrict__ xc_off,
               const float* __restrict__ yc_off,
               const float* __restrict__ yc_on,
               const float* __restrict__ xt,
               const float* __restrict__ means,
               const float* __restrict__ logit_p,
               float* __restrict__ out)
{
    const int blocksPerBatch = MM / PTS;
    const int b     = blockIdx.x / blocksPerBatch;
    const int pbase = (blockIdx.x % blocksPerBatch) * PTS;
    const int wave  = threadIdx.x >> 6;
    const int lane  = threadIdx.x & 63;
    const int m     = pbase + lane;

    const float2 pt = ((const float2*)xt)[b * MM + m];
    const float px = pt.x, py = pt.y;

    const float2* __restrict__ cxy = ((const float2*)xc_off) + (size_t)b * NN;
    const float*  __restrict__ cv  = yc_off + (size_t)b * NN;

    float best = 3.4e38f, bestv = 0.f;
    const int j0 = wave * SLICE;
    for (int t = 0; t < SLICE; t += 8) {
#pragma unroll
        for (int u = 0; u < 8; ++u) {
            const int j = j0 + t + u;
            const float2 c = cxy[j];
            const float  v = cv[j];
            const float dx = px - c.x;
            const float dy = py - c.y;
            const float d2 = fmaf(dx, dx, dy * dy);
            const bool lt = d2 < best;
            best  = lt ? d2 : best;
            bestv = lt ? v  : bestv;
        }
    }

    __shared__ float sd2[WAVES][PTS];
    __shared__ float sv [WAVES][PTS];
    sd2[wave][lane] = best;
    sv [wave][lane] = bestv;
    __syncthreads();

    if (threadIdx.x < PTS) {
        float bd = sd2[0][lane];
        float bv = sv [0][lane];
#pragma unroll
        for (int wv = 1; wv < WAVES; ++wv) {
            if (sd2[wv][lane] < bd) { bd = sd2[wv][lane]; bv = sv[wv][lane]; }
        }
        out[(size_t)b * MM + m] = epilogue(yc_on, means, logit_p, b, px, py, bv);
    }
}

// ---------------------------------------------------------------------------
extern "C" void kernel_launch(void* const* d_in, const int* in_sizes, int n_in,
                              void* d_out, int out_size, void* d_ws, size_t ws_size,
                              hipStream_t stream) {
    const float* xc_off = (const float*)d_in[0];   // (B,N,2)
    const float* yc_off = (const float*)d_in[1];   // (B,N)
    // d_in[2] = xc_on_grid (regular linspace grid, not needed)
    const float* yc_on  = (const float*)d_in[3];   // (B,H,W)
    const float* xt     = (const float*)d_in[4];   // (B,M,2)
    const float* logit  = (const float*)d_in[5];   // scalar
    float* out = (float*)d_out;

    float* means = (float*)d_ws;

    if (ws_size >= WS_NEEDED) {
        int*    starts   = (int*)((char*)d_ws + WS_STARTS_OFF);
        int*    cursors  = (int*)((char*)d_ws + WS_CURSORS_OFF);
        float4* cellData = (float4*)((char*)d_ws + WS_CELLS_OFF);
        int*    bh       = (int*)((char*)d_ws + WS_BH_OFF);

        void* args[] = {
            (void*)&xc_off, (void*)&yc_off, (void*)&yc_on, (void*)&xt,
            (void*)&logit, (void*)&means, (void*)&starts, (void*)&cursors,
            (void*)&cellData, (void*)&bh, (void*)&out
        };
        hipLaunchCooperativeKernel((const void*)coop_kernel,
                                   dim3(256), dim3(1024), args, 0, stream);
    } else {
        mean_kernel<<<BB, 256, 0, stream>>>(yc_on, means);
        nn_kernel<<<BB * (MM / PTS), WAVES * 64, 0, stream>>>(
            xc_off, yc_off, yc_on, xt, means, logit, out);
    }
}

// Round 8
// 102.774 us; speedup vs baseline: 4.1604x; 4.1604x over previous
//
#include <hip/hip_runtime.h>
#include <math.h>
#include <float.h>

#define BB 8
#define NN 8192
#define MM 4096
#define HH 128
#define WW 128

#define G    32
#define GG   (G * G)
#define CELL (1.0f / G)

// ws layout (16B-aligned sections):
//   [0, 32)              means (8 floats)
//   [256, 33056)         starts (B x (GG+1) ints)
//   [33056, +1MiB)       cellData (B x N float4: x, y, val, idx-bits)
#define WS_STARTS_OFF 256
#define WS_CELLS_OFF  33056
#define WS_NEEDED     (WS_CELLS_OFF + (size_t)BB * NN * 16)

__device__ __forceinline__ int clampi(int v, int lo, int hi) {
    return v < lo ? lo : (v > hi ? hi : v);
}

// ---------------------------------------------------------------------------
// Kernel 1: fused binning + per-batch mean. One block per batch.
// Binning is SINGLE-atomic-pass: atomicAdd's return value in the count pass
// is the point's within-cell rank; after the exclusive scan, position =
// excl_start[cell] + rank (plain LDS read, no cursor atomics). yc_off is
// prefetched in pass 1 so the scatter pass issues no global loads.
// Rank order within a cell is nondeterministic — harmless, since the query
// uses the order-independent lexicographic (d2, idx) min (absmax 0.0,
// R3-R6). Scan + mean numerics unchanged (bit-validated R1/R3-R6).
// ---------------------------------------------------------------------------
__global__ __launch_bounds__(1024)
void bin_mean_kernel(const float* __restrict__ xc_off,   // (B,N,2)
                     const float* __restrict__ yc_off,   // (B,N)
                     const float* __restrict__ yc_on,    // (B,H,W)
                     int* __restrict__ starts,           // (B, GG+1)
                     float4* __restrict__ cellData,      // (B, N)
                     float* __restrict__ means)          // (B)
{
    const int b   = blockIdx.x;
    const int tid = threadIdx.x;
    __shared__ int   cnt[GG];
    __shared__ int   wsum[16];
    __shared__ float partial[4];
    cnt[tid] = 0;
    __syncthreads();

    const float2* __restrict__ cxy = ((const float2*)xc_off) + (size_t)b * NN;
    const float*  __restrict__ cv  = yc_off + (size_t)b * NN;
    float2 pts [NN / 1024];
    float  vals[NN / 1024];
    int    cells[NN / 1024];
    int    rank[NN / 1024];
#pragma unroll
    for (int k = 0; k < NN / 1024; ++k) {
        const int i = tid + k * 1024;
        float2 c = cxy[i];
        vals[k] = cv[i];                       // prefetch value for scatter
        int gx = clampi((int)(c.x * (float)G), 0, G - 1);
        int gy = clampi((int)(c.y * (float)G), 0, G - 1);
        pts[k]   = c;
        cells[k] = gx * G + gy;
        rank[k]  = atomicAdd(&cnt[cells[k]], 1);   // old value = in-cell rank
    }
    __syncthreads();

    // exclusive scan over the 1024 cell counts (validated R3-R6)
    const int orig = cnt[tid];
    int x = orig;
    const int lane = tid & 63, wid = tid >> 6;
    for (int off = 1; off < 64; off <<= 1) {
        int y = __shfl_up(x, off, 64);
        if (lane >= off) x += y;
    }
    if (lane == 63) wsum[wid] = x;
    __syncthreads();
    if (tid < 16) {
        int w = wsum[tid];
        for (int off = 1; off < 16; off <<= 1) {
            int y = __shfl_up(w, off, 16);
            if (tid >= off) w += y;
        }
        wsum[tid] = w;
    }
    __syncthreads();
    const int incl = x + (wid ? wsum[wid - 1] : 0);
    const int excl = incl - orig;
    starts[b * (GG + 1) + tid] = excl;
    if (tid == GG - 1) starts[b * (GG + 1) + GG] = incl;   // == N
    __syncthreads();
    cnt[tid] = excl;   // per-cell base for placement (read-only below)
    __syncthreads();

    // scatter: position = base[cell] + rank (no atomics, no global loads)
#pragma unroll
    for (int k = 0; k < NN / 1024; ++k) {
        const int i = tid + k * 1024;
        const int pos = cnt[cells[k]] + rank[k];
        cellData[(size_t)b * NN + pos] =
            make_float4(pts[k].x, pts[k].y, vals[k], __int_as_float(i));
    }

    // ---- mean phase (first 256 threads; bit-exact summation order) ----
    float s = 0.f;
    if (tid < 256) {
        const float* p = yc_on + b * (HH * WW);
        for (int i = tid; i < HH * WW; i += 256) s += p[i];
        for (int off = 32; off > 0; off >>= 1) s += __shfl_down(s, off, 64);
    }
    if (tid < 256 && (tid & 63) == 0) partial[tid >> 6] = s;
    __syncthreads();
    if (tid == 0) {
        float t = 0.f;
        for (int i = 0; i < 4; ++i) t += partial[i];
        means[b] = t * (1.0f / (HH * WW));
    }
}

// ---------------------------------------------------------------------------
// Bilinear + mix epilogue (validated bit-exact in R1/R3-R6).
// ---------------------------------------------------------------------------
__device__ __forceinline__ float epilogue(const float* __restrict__ yc_on,
                                          const float* __restrict__ means,
                                          const float* __restrict__ logit_p,
                                          int b, float px, float py, float bv) {
    const float* __restrict__ vals = yc_on + (size_t)b * HH * WW;
    const float x = px, y = py;
    int ix = clampi((int)floorf(x * 127.0f), 0, 126);
    int iy = clampi((int)floorf(y * 127.0f), 0, 126);
    const float x0 = (float)ix * (1.0f / 127.0f);
    const float x1 = (float)(ix + 1) * (1.0f / 127.0f);
    const float y0 = (float)iy * (1.0f / 127.0f);
    const float y1 = (float)(iy + 1) * (1.0f / 127.0f);
    const float wx = (x - x0) / (x1 - x0);
    const float wy = (y - y0) / (y1 - y0);
    const float v00 = vals[ix * WW + iy];
    const float v01 = vals[ix * WW + iy + 1];
    const float v10 = vals[(ix + 1) * WW + iy];
    const float v11 = vals[(ix + 1) * WW + iy + 1];
    float vi = (1.f - wx) * (1.f - wy) * v00
             + (1.f - wx) * wy         * v01
             + wx         * (1.f - wy) * v10
             + wx         * wy         * v11;
    const bool oob = (x < 0.f) || (x > 1.f) || (y < 0.f) || (y > 1.f);
    const float yon = oob ? means[b] : vi;
    const float l   = logit_p[0];
    const float mix = 1.f / (1.f + expf(-l));
    return mix * bv + (1.f - mix) * yon;
}

// ---------------------------------------------------------------------------
// Kernel 2: NN query — 2 queries per wave (independent 32-lane halves),
// unchanged from R5/R6 (validated absmax 0.0). Lanes of a half scan cell-rows
// in parallel, then a 5-step xor-shuffle lexicographic (d2, idx) argmin.
// Ring re-scan is idempotent under the order-independent lexicographic min.
// ---------------------------------------------------------------------------
__global__ __launch_bounds__(256)
void query_kernel(const int* __restrict__ starts,
                  const float4* __restrict__ cellData,
                  const float* __restrict__ yc_on,    // (B,H,W)
                  const float* __restrict__ xt,       // (B,M,2)
                  const float* __restrict__ means,    // (B)
                  const float* __restrict__ logit_p,  // (1)
                  float* __restrict__ out)            // (B,M)
{
    const int lane32 = threadIdx.x & 31;
    const int pid = blockIdx.x * 8 + (threadIdx.x >> 5);   // half-wave id
    const int b = pid >> 12;                               // / MM
    const int m = pid & (MM - 1);

    const float2 pt = ((const float2*)xt)[pid];
    const float px = pt.x, py = pt.y;

    const int cx = clampi((int)(px * (float)G), 0, G - 1);
    const int cy = clampi((int)(py * (float)G), 0, G - 1);

    const int*    __restrict__ st = starts + b * (GG + 1);
    const float4* __restrict__ cd = cellData + (size_t)b * NN;

    float bd = FLT_MAX;
    float bv = 0.f;
    int   bi = 0x7fffffff;

    for (int r = 1; r <= G; ++r) {
        const int gx0 = clampi(cx - r, 0, G - 1);
        const int gx1 = clampi(cx + r, 0, G - 1);
        const int gy0 = clampi(cy - r, 0, G - 1);
        const int gy1 = clampi(cy + r, 0, G - 1);

        for (int gx = gx0; gx <= gx1; ++gx) {
            const int lo = st[gx * G + gy0];
            const int hi = st[gx * G + gy1 + 1];
            for (int j = lo + lane32; j < hi; j += 32) {  // parallel row gather
                const float4 c = cd[j];
                const float dx = px - c.x;
                const float dy = py - c.y;
                const float d2 = fmaf(dx, dx, dy * dy);
                const int   ci = __float_as_int(c.w);
                if (d2 < bd || (d2 == bd && ci < bi)) { bd = d2; bv = c.z; bi = ci; }
            }
        }

        // half-wave lexicographic argmin (offsets 1..16 stay in each half)
        for (int off = 1; off < 32; off <<= 1) {
            const float od = __shfl_xor(bd, off, 64);
            const float ov = __shfl_xor(bv, off, 64);
            const int   oi = __shfl_xor(bi, off, 64);
            if (od < bd || (od == bd && oi < bi)) { bd = od; bv = ov; bi = oi; }
        }

        // after square r, all unseen candidates are >= r*CELL away
        const float rr = (float)r * CELL;
        if (rr * rr > bd) break;
    }

    if (lane32 == 0)
        out[(size_t)b * MM + m] = epilogue(yc_on, means, logit_p, b, px, py, bv);
}

// ---------------------------------------------------------------------------
// Fallback: R1 brute-force NN (validated absmax 0.0) — only if ws too small.
// ---------------------------------------------------------------------------
#define WAVES 8
#define PTS 64
#define SLICE (NN / WAVES)

__global__ void mean_kernel(const float* __restrict__ yc_on,
                            float* __restrict__ means) {
    int b = blockIdx.x;
    const float* p = yc_on + b * (HH * WW);
    float s = 0.f;
    for (int i = threadIdx.x; i < HH * WW; i += blockDim.x) s += p[i];
    for (int off = 32; off > 0; off >>= 1) s += __shfl_down(s, off, 64);
    __shared__ float partial[4];
    int wave = threadIdx.x >> 6;
    if ((threadIdx.x & 63) == 0) partial[wave] = s;
    __syncthreads();
    if (threadIdx.x == 0) {
        float t = 0.f;
        int nw = blockDim.x >> 6;
        for (int i = 0; i < nw; ++i) t += partial[i];
        means[b] = t * (1.0f / (HH * WW));
    }
}

__global__ __launch_bounds__(WAVES * 64)
void nn_kernel(const float* __restrict__ xc_off,
               const float* __restrict__ yc_off,
               const float* __restrict__ yc_on,
               const float* __restrict__ xt,
               const float* __restrict__ means,
               const float* __restrict__ logit_p,
               float* __restrict__ out)
{
    const int blocksPerBatch = MM / PTS;
    const int b     = blockIdx.x / blocksPerBatch;
    const int pbase = (blockIdx.x % blocksPerBatch) * PTS;
    const int wave  = threadIdx.x >> 6;
    const int lane  = threadIdx.x & 63;
    const int m     = pbase + lane;

    const float2 pt = ((const float2*)xt)[b * MM + m];
    const float px = pt.x, py = pt.y;

    const float2* __restrict__ cxy = ((const float2*)xc_off) + (size_t)b * NN;
    const float*  __restrict__ cv  = yc_off + (size_t)b * NN;

    float best = 3.4e38f, bestv = 0.f;
    const int j0 = wave * SLICE;
    for (int t = 0; t < SLICE; t += 8) {
#pragma unroll
        for (int u = 0; u < 8; ++u) {
            const int j = j0 + t + u;
            const float2 c = cxy[j];
            const float  v = cv[j];
            const float dx = px - c.x;
            const float dy = py - c.y;
            const float d2 = fmaf(dx, dx, dy * dy);
            const bool lt = d2 < best;
            best  = lt ? d2 : best;
            bestv = lt ? v  : bestv;
        }
    }

    __shared__ float sd2[WAVES][PTS];
    __shared__ float sv [WAVES][PTS];
    sd2[wave][lane] = best;
    sv [wave][lane] = bestv;
    __syncthreads();

    if (threadIdx.x < PTS) {
        float bd = sd2[0][lane];
        float bv = sv [0][lane];
#pragma unroll
        for (int wv = 1; wv < WAVES; ++wv) {
            if (sd2[wv][lane] < bd) { bd = sd2[wv][lane]; bv = sv[wv][lane]; }
        }
        out[(size_t)b * MM + m] = epilogue(yc_on, means, logit_p, b, px, py, bv);
    }
}

// ---------------------------------------------------------------------------
extern "C" void kernel_launch(void* const* d_in, const int* in_sizes, int n_in,
                              void* d_out, int out_size, void* d_ws, size_t ws_size,
                              hipStream_t stream) {
    const float* xc_off = (const float*)d_in[0];   // (B,N,2)
    const float* yc_off = (const float*)d_in[1];   // (B,N)
    // d_in[2] = xc_on_grid (regular linspace grid, not needed)
    const float* yc_on  = (const float*)d_in[3];   // (B,H,W)
    const float* xt     = (const float*)d_in[4];   // (B,M,2)
    const float* logit  = (const float*)d_in[5];   // scalar
    float* out = (float*)d_out;

    float* means = (float*)d_ws;

    if (ws_size >= WS_NEEDED) {
        int*    starts   = (int*)((char*)d_ws + WS_STARTS_OFF);
        float4* cellData = (float4*)((char*)d_ws + WS_CELLS_OFF);

        bin_mean_kernel<<<BB, 1024, 0, stream>>>(
            xc_off, yc_off, yc_on, starts, cellData, means);
        query_kernel<<<(BB * MM) / 8, 256, 0, stream>>>(
            starts, cellData, yc_on, xt, means, logit, out);
    } else {
        mean_kernel<<<BB, 256, 0, stream>>>(yc_on, means);
        nn_kernel<<<BB * (MM / PTS), WAVES * 64, 0, stream>>>(
            xc_off, yc_off, yc_on, xt, means, logit, out);
    }
}